// Round 7
// baseline (727.694 us; speedup 1.0000x reference)
//
#include <hip/hip_runtime.h>

typedef __bf16 bf16_t;
typedef __bf16 bf16x8 __attribute__((ext_vector_type(8)));
typedef __bf16 bf16x4 __attribute__((ext_vector_type(4)));
typedef float  f32x4  __attribute__((ext_vector_type(4)));
typedef int    i32x4  __attribute__((ext_vector_type(4)));

#define B_      16
#define L_      2048
#define D_      128
#define QTB     128              // q rows per block = 8 waves x 16
#define NEGINF  (-1.0e9f)
#define SCALE   0.08838834764831845f   // 1/sqrt(128)

// ---------------------------------------------------------------------------
// Prep kernel: blocks 0..255  : V fp32 [B][L][D] -> bf16 VT [B][D][L]
//              blocks 256..511: K fp32 -> bf16 row-major
// ---------------------------------------------------------------------------
__global__ __launch_bounds__(256) void prep_kernel(
    const float* __restrict__ k, const float* __restrict__ v,
    bf16_t* __restrict__ kb, bf16_t* __restrict__ vt)
{
    __shared__ bf16_t tile[128 * 144];
    const int tid = threadIdx.x;
    const int bid = (int)blockIdx.x;

    if (bid < 256) {
        const int b  = bid >> 4;
        const int l0 = (bid & 15) * 128;
        #pragma unroll
        for (int it = 0; it < 16; ++it) {
            int idx = tid + it * 256;
            int row = idx >> 5;
            int dc4 = idx & 31;
            f32x4 x = __builtin_nontemporal_load(
                (const f32x4*)(v + ((size_t)b * L_ + l0 + row) * (size_t)D_ + dc4 * 4));
            #pragma unroll
            for (int i = 0; i < 4; ++i) tile[(dc4 * 4 + i) * 144 + row] = (bf16_t)x[i];
        }
        __syncthreads();
        #pragma unroll
        for (int it = 0; it < 8; ++it) {
            int idx = tid + it * 256;
            int d   = idx >> 4;
            int lc  = idx & 15;
            bf16x8 vec = *(const bf16x8*)&tile[d * 144 + lc * 8];
            *(bf16x8*)(vt + ((size_t)b * D_ + d) * (size_t)L_ + l0 + lc * 8) = vec;
        }
    } else {
        const int idx0 = (bid - 256) * 256 + tid;
        #pragma unroll
        for (int c = 0; c < 16; ++c) {
            int idx = idx0 + c * 65536;
            f32x4 x = __builtin_nontemporal_load((const f32x4*)(k + (size_t)idx * 4));
            bf16x4 o;
            #pragma unroll
            for (int i = 0; i < 4; ++i) o[i] = (bf16_t)x[i];
            *(bf16x4*)(kb + (size_t)idx * 4) = o;
        }
    }
}

// ---------------------------------------------------------------------------
// Main kernel: 256 blocks (1/CU), 8 waves, 128 q-rows/block, NO barriers.
// Pass 1: QK^T + online masked max/sum. K pipeline depth-4 subs, mask depth-4.
// Pass 2: recompute QK^T, p=exp fp32 -> olds staging -> coalesced NT attn
//         flush per c4; PV with staggered V-frag prefetch.
// ---------------------------------------------------------------------------
template <bool WS>
__global__ __launch_bounds__(512) void sdpa_kernel(
    const float* __restrict__ q, const float* __restrict__ k,
    const float* __restrict__ v, const int* __restrict__ mask,
    const bf16_t* __restrict__ kb, const bf16_t* __restrict__ vt,
    float* __restrict__ out, float* __restrict__ attn)
{
    __shared__ unsigned mlds[8 * 1024];     // 32 KB packed mask bits (per-wave)
    __shared__ bf16_t   plds[8][16][40];    // 10 KB P bounce tile (per-wave)
    __shared__ float    olds[8][16][132];   // 66 KB attn staging (per-wave)

    const int tid = threadIdx.x;
    const int w   = tid >> 6;
    const int l   = tid & 63;
    const int li  = l & 15;
    const int lg  = l >> 4;

    // XCD-chunked bijective swizzle (256 % 8 == 0)
    const int bid  = (int)blockIdx.x;
    const int bid2 = (bid & 7) * 32 + (bid >> 3);
    const int b    = bid2 >> 4;
    const int qt   = bid2 & 15;
    const int qbase = qt * QTB;

    const size_t bq   = (size_t)b * L_;
    const int    qrow = qbase + w * 16 + li;

    const float*  qp   = q  + (bq + qbase) * (size_t)D_;
    const bf16_t* kbp  = kb + bq * (size_t)D_;
    const float*  kp   = k  + bq * (size_t)D_;
    const bf16_t* vtp  = vt + (size_t)b * D_ * (size_t)L_;
    const float*  vp   = v  + bq * (size_t)D_;
    const int*    mrow = mask + (bq + qrow) * (size_t)L_;
    float* attnbase = attn + (bq + qbase + (size_t)w * 16) * (size_t)L_;
    float* outp     = out  + (bq + qbase) * (size_t)D_;

    // ---------------- Q B-fragments (pre-scaled by 1/temper)
    bf16x8 aq[4];
    #pragma unroll
    for (int ds = 0; ds < 4; ++ds) {
        const float* p = qp + (size_t)(w * 16 + li) * D_ + ds * 32 + lg * 8;
        f32x4 x0 = *(const f32x4*)p;
        f32x4 x1 = *(const f32x4*)(p + 4);
        bf16x8 a;
        #pragma unroll
        for (int u = 0; u < 4; ++u) {
            a[u]     = (bf16_t)(x0[u] * SCALE);
            a[4 + u] = (bf16_t)(x1[u] * SCALE);
        }
        aq[ds] = a;
    }

    // K tile loader (tile t = k rows 16t..16t+15 -> A-frag, 16 VGPR)
    auto ldK = [&](int t, bf16x8* dst) {
        if (WS) {
            const bf16_t* p = kbp + (size_t)(t * 16 + li) * D_;
            #pragma unroll
            for (int ds = 0; ds < 4; ++ds) dst[ds] = *(const bf16x8*)(p + ds * 32 + lg * 8);
        } else {
            const float* p = kp + (size_t)(t * 16 + li) * D_;
            #pragma unroll
            for (int ds = 0; ds < 4; ++ds) {
                f32x4 x0 = *(const f32x4*)(p + ds * 32 + lg * 8);
                f32x4 x1 = *(const f32x4*)(p + ds * 32 + lg * 8 + 4);
                bf16x8 a;
                #pragma unroll
                for (int u = 0; u < 4; ++u) { a[u] = (bf16_t)x0[u]; a[4+u] = (bf16_t)x1[u]; }
                dst[ds] = a;
            }
        }
    };

    // ================= PASS 1: online masked max/sum (depth-4 pipeline) ======
    float m_run = -3.4e38f, l_run = 0.f;
    {
        bf16x8 KS[4][2][4];     // 4 sub-slots x 2 tiles -> 128 VGPR
        i32x4  MS[4][2];        // 4 sub-slots of mask (32B each)

        #pragma unroll
        for (int s = 0; s < 4; ++s) {
            ldK(2 * s,     KS[s][0]);
            ldK(2 * s + 1, KS[s][1]);
            MS[s][0] = __builtin_nontemporal_load((const i32x4*)(mrow + s * 32 + lg * 4));
            MS[s][1] = __builtin_nontemporal_load((const i32x4*)(mrow + s * 32 + 16 + lg * 4));
        }

        #pragma unroll 1
        for (int c4 = 0; c4 < 16; ++c4) {
            unsigned mword = 0;
            #pragma unroll
            for (int sub = 0; sub < 4; ++sub) {
                const int c = c4 * 4 + sub;
                f32x4 a0 = {0.f,0.f,0.f,0.f}, a1 = {0.f,0.f,0.f,0.f};
                #pragma unroll
                for (int ds = 0; ds < 4; ++ds)
                    a0 = __builtin_amdgcn_mfma_f32_16x16x32_bf16(KS[sub][0][ds], aq[ds], a0, 0, 0, 0);
                #pragma unroll
                for (int ds = 0; ds < 4; ++ds)
                    a1 = __builtin_amdgcn_mfma_f32_16x16x32_bf16(KS[sub][1][ds], aq[ds], a1, 0, 0, 0);

                i32x4 va = MS[sub][0], vb_ = MS[sub][1];
                if (c4 < 15) {              // reload slot for sub c+4 (3-sub lead)
                    ldK(2 * c + 8, KS[sub][0]);
                    ldK(2 * c + 9, KS[sub][1]);
                    MS[sub][0] = __builtin_nontemporal_load((const i32x4*)(mrow + (c + 4) * 32 + lg * 4));
                    MS[sub][1] = __builtin_nontemporal_load((const i32x4*)(mrow + (c + 4) * 32 + 16 + lg * 4));
                }

                unsigned byte =
                    (va[0]  != 0 ?   1u : 0u) | (va[1]  != 0 ?   2u : 0u) |
                    (va[2]  != 0 ?   4u : 0u) | (va[3]  != 0 ?   8u : 0u) |
                    (vb_[0] != 0 ?  16u : 0u) | (vb_[1] != 0 ?  32u : 0u) |
                    (vb_[2] != 0 ?  64u : 0u) | (vb_[3] != 0 ? 128u : 0u);

                float s0[4], s1[4];
                #pragma unroll
                for (int r = 0; r < 4; ++r) {
                    s0[r] = a0[r] + (((byte >> r)       & 1u) ? 0.f : NEGINF);
                    s1[r] = a1[r] + (((byte >> (4 + r)) & 1u) ? 0.f : NEGINF);
                }
                float mx = fmaxf(fmaxf(fmaxf(s0[0], s0[1]), fmaxf(s0[2], s0[3])),
                                 fmaxf(fmaxf(s1[0], s1[1]), fmaxf(s1[2], s1[3])));
                mx = fmaxf(mx, m_run);
                float acc = 0.f;
                #pragma unroll
                for (int r = 0; r < 4; ++r)
                    acc += __expf(s0[r] - mx) + __expf(s1[r] - mx);
                l_run = l_run * __expf(m_run - mx) + acc;
                m_run = mx;
                mword |= byte << (sub * 8);
            }
            mlds[w * 1024 + c4 * 64 + l] = mword;
        }
    }

    // merge m/sum across the 4 lane-groups
    #pragma unroll
    for (int off = 16; off < 64; off <<= 1) {
        float mo = __shfl_xor(m_run, off);
        float lo = __shfl_xor(l_run, off);
        float mn = fmaxf(m_run, mo);
        l_run = l_run * __expf(m_run - mn) + lo * __expf(mo - mn);
        m_run = mn;
    }
    const float inv_l = 1.f / l_run;

    // ================= PASS 2: recompute + staged attn write + PV ============
    f32x4 pv[8];
    #pragma unroll
    for (int dt = 0; dt < 8; ++dt) pv[dt] = {0.f,0.f,0.f,0.f};

    auto ldVT = [&](int dt, int c, bf16x8& dst) {
        if (WS) {
            dst = *(const bf16x8*)(vtp + (size_t)(dt * 16 + li) * L_ + c * 32 + lg * 8);
        } else {
            bf16x8 a;
            #pragma unroll
            for (int u = 0; u < 8; ++u)
                a[u] = (bf16_t)vp[(size_t)(c * 32 + lg * 8 + u) * D_ + dt * 16 + li];
            dst = a;
        }
    };

    {
        bf16x8 KP[2][2][4];     // 2 sub-slots x 2 tiles
        ldK(0, KP[0][0]); ldK(1, KP[0][1]);
        ldK(2, KP[1][0]); ldK(3, KP[1][1]);
        bf16x8 vlo[4], vhi[4];
        #pragma unroll
        for (int dt = 0; dt < 4; ++dt) ldVT(dt, 0, vlo[dt]);

        #pragma unroll 1
        for (int c4 = 0; c4 < 16; ++c4) {
            unsigned mword = mlds[w * 1024 + c4 * 64 + l];
            #pragma unroll
            for (int sub = 0; sub < 4; ++sub) {
                const int c  = c4 * 4 + sub;
                const int sl = sub & 1;

                f32x4 a0 = {0.f,0.f,0.f,0.f}, a1 = {0.f,0.f,0.f,0.f};
                #pragma unroll
                for (int ds = 0; ds < 4; ++ds)
                    a0 = __builtin_amdgcn_mfma_f32_16x16x32_bf16(KP[sl][0][ds], aq[ds], a0, 0, 0, 0);
                #pragma unroll
                for (int ds = 0; ds < 4; ++ds)
                    a1 = __builtin_amdgcn_mfma_f32_16x16x32_bf16(KP[sl][1][ds], aq[ds], a1, 0, 0, 0);
                if (c < 62) { ldK(2 * c + 4, KP[sl][0]); ldK(2 * c + 5, KP[sl][1]); }

                // issue current-sub hi V frags early
                #pragma unroll
                for (int dt = 0; dt < 4; ++dt) ldVT(dt + 4, c, vhi[dt]);

                const unsigned byte = (mword >> (sub * 8)) & 0xffu;
                f32x4 o0, o1; bf16x4 pb0, pb1;
                #pragma unroll
                for (int r = 0; r < 4; ++r) {
                    float sa = a0[r] + (((byte >> r)       & 1u) ? 0.f : NEGINF);
                    float sb = a1[r] + (((byte >> (4 + r)) & 1u) ? 0.f : NEGINF);
                    float p0 = __expf(sa - m_run);
                    float p1 = __expf(sb - m_run);
                    o0[r] = p0 * inv_l;  o1[r] = p1 * inv_l;
                    pb0[r] = (bf16_t)p0; pb1[r] = (bf16_t)p1;
                }
                // stage normalized attn into per-wave LDS tile
                *(f32x4*)&olds[w][li][(c & 3) * 32 + lg * 4]      = o0;
                *(f32x4*)&olds[w][li][(c & 3) * 32 + 16 + lg * 4] = o1;

                // C-layout -> A-frag bounce (per-wave LDS)
                *(bf16x4*)&plds[w][li][lg * 4]      = pb0;
                *(bf16x4*)&plds[w][li][16 + lg * 4] = pb1;
                bf16x8 pa = *(const bf16x8*)&plds[w][li][lg * 8];

                #pragma unroll
                for (int dt = 0; dt < 4; ++dt)
                    pv[dt] = __builtin_amdgcn_mfma_f32_16x16x32_bf16(pa, vlo[dt], pv[dt], 0, 0, 0);
                // prefetch next sub's lo V frags (1-sub lead)
                if (c < 63) {
                    #pragma unroll
                    for (int dt = 0; dt < 4; ++dt) ldVT(dt, c + 1, vlo[dt]);
                }
                #pragma unroll
                for (int dt = 0; dt < 4; ++dt)
                    pv[dt + 4] = __builtin_amdgcn_mfma_f32_16x16x32_bf16(pa, vhi[dt], pv[dt + 4], 0, 0, 0);
            }

            // flush olds -> attn, full-line NT stores (lane: row=l>>2, 128B seg)
            {
                const int frow = l >> 2;
                const int fcc  = (l & 3) * 32;
                float* arow = attnbase + (size_t)frow * L_ + c4 * 128 + fcc;
                #pragma unroll
                for (int j = 0; j < 8; ++j) {
                    f32x4 x = *(const f32x4*)&olds[w][frow][fcc + j * 4];
                    __builtin_nontemporal_store(x, (f32x4*)(arow + j * 4));
                }
            }
        }
    }

    // ---------------- Epilogue: out[q][d] = pv * inv_l[q]
    #pragma unroll
    for (int r = 0; r < 4; ++r) {
        const float il = __shfl(inv_l, lg * 4 + r);
        float* orow = outp + (size_t)(w * 16 + lg * 4 + r) * D_ + li;
        #pragma unroll
        for (int dt = 0; dt < 8; ++dt)
            __builtin_nontemporal_store(pv[dt][r] * il, orow + dt * 16);
    }
}

extern "C" void kernel_launch(void* const* d_in, const int* in_sizes, int n_in,
                              void* d_out, int out_size, void* d_ws, size_t ws_size,
                              hipStream_t stream) {
    const float* q    = (const float*)d_in[0];
    const float* k    = (const float*)d_in[1];
    const float* v    = (const float*)d_in[2];
    const int*   mask = (const int*)d_in[3];

    float* out  = (float*)d_out;
    float* attn = out + (size_t)B_ * L_ * D_;

    const size_t VT_BYTES = (size_t)B_ * D_ * L_ * 2;   // 8 MB
    const size_t KB_BYTES = (size_t)B_ * L_ * D_ * 2;   // 8 MB
    const bool ws_ok = ws_size >= VT_BYTES + KB_BYTES;
    bf16_t* vt = (bf16_t*)d_ws;
    bf16_t* kb = (bf16_t*)((char*)d_ws + VT_BYTES);

    if (ws_ok) {
        hipLaunchKernelGGL(prep_kernel, dim3(512), dim3(256), 0, stream, k, v, kb, vt);
        hipLaunchKernelGGL(sdpa_kernel<true>, dim3(256), dim3(512), 0, stream,
                           q, k, v, mask, kb, vt, out, attn);
    } else {
        hipLaunchKernelGGL(sdpa_kernel<false>, dim3(256), dim3(512), 0, stream,
                           q, k, v, mask, kb, vt, out, attn);
    }
}

// Round 8
// 183.186 us; speedup vs baseline: 3.9724x; 3.9724x over previous
//
#include <hip/hip_runtime.h>

typedef __bf16 bf16_t;
typedef __bf16 bf16x8 __attribute__((ext_vector_type(8)));
typedef __bf16 bf16x4 __attribute__((ext_vector_type(4)));
typedef float  f32x4  __attribute__((ext_vector_type(4)));
typedef int    i32x4  __attribute__((ext_vector_type(4)));

#define B_      16
#define L_      2048
#define D_      128
#define QTB     128              // q rows per block = 8 waves x 16
#define NEGINF  (-1.0e9f)
#define SCALE   0.08838834764831845f   // 1/sqrt(128)

#define MFMA_BF16 __builtin_amdgcn_mfma_f32_16x16x32_bf16

// lgkm drain (ds_writes visible to peers after barrier) WITHOUT vmcnt drain
// (global loads for future chunks stay in flight across the barrier).
#define BARRIER() do { asm volatile("s_waitcnt lgkmcnt(0)" ::: "memory"); \
                       __builtin_amdgcn_s_barrier(); } while (0)

// ---------------------------------------------------------------------------
// Prep kernel: blocks 0..255  : V fp32 [B][L][D] -> bf16 VT [B][D][L]
//              blocks 256..511: K fp32 -> bf16 row-major
// ---------------------------------------------------------------------------
__global__ __launch_bounds__(256) void prep_kernel(
    const float* __restrict__ k, const float* __restrict__ v,
    bf16_t* __restrict__ kb, bf16_t* __restrict__ vt)
{
    __shared__ bf16_t tile[128 * 144];
    const int tid = threadIdx.x;
    const int bid = (int)blockIdx.x;

    if (bid < 256) {
        const int b  = bid >> 4;
        const int l0 = (bid & 15) * 128;
        #pragma unroll
        for (int it = 0; it < 16; ++it) {
            int idx = tid + it * 256;
            int row = idx >> 5;
            int dc4 = idx & 31;
            f32x4 x = __builtin_nontemporal_load(
                (const f32x4*)(v + ((size_t)b * L_ + l0 + row) * (size_t)D_ + dc4 * 4));
            #pragma unroll
            for (int i = 0; i < 4; ++i) tile[(dc4 * 4 + i) * 144 + row] = (bf16_t)x[i];
        }
        __syncthreads();
        #pragma unroll
        for (int it = 0; it < 8; ++it) {
            int idx = tid + it * 256;
            int d   = idx >> 4;
            int lc  = idx & 15;
            bf16x8 vec = *(const bf16x8*)&tile[d * 144 + lc * 8];
            *(bf16x8*)(vt + ((size_t)b * D_ + d) * (size_t)L_ + l0 + lc * 8) = vec;
        }
    } else {
        const int idx0 = (bid - 256) * 256 + tid;
        #pragma unroll
        for (int c = 0; c < 16; ++c) {
            int idx = idx0 + c * 65536;
            f32x4 x = __builtin_nontemporal_load((const f32x4*)(k + (size_t)idx * 4));
            bf16x4 o;
            #pragma unroll
            for (int i = 0; i < 4; ++i) o[i] = (bf16_t)x[i];
            *(bf16x4*)(kb + (size_t)idx * 4) = o;
        }
    }
}

// ---------------------------------------------------------------------------
// Main kernel: 256 blocks (1/CU), 8 waves, 128 q-rows.
// All K/V/mask staged cooperatively into LDS (triple-buffered, stage distance
// 2, one raw barrier per chunk). Two passes over k: online masked max/sum,
// then recompute + fp32 attn write + PV.
// ---------------------------------------------------------------------------
template <bool WS>
__global__ __launch_bounds__(512, 1) void sdpa_kernel(
    const float* __restrict__ q, const float* __restrict__ k,
    const float* __restrict__ v, const int* __restrict__ mask,
    const bf16_t* __restrict__ kb, const bf16_t* __restrict__ vt,
    float* __restrict__ out, float* __restrict__ attn)
{
    __shared__ char     KstRaw[3 * 8192];    // 24KB  K slabs [32][128] bf16, XOR-swz
    __shared__ char     MVRaw[3 * 16384];    // 48KB  p1: mask [128][32] i32 XOR-swz; p2: V [128][32] bf16
    __shared__ unsigned mlds[8 * 1024];      // 32KB  packed mask bits (per-wave regions)
    __shared__ bf16_t   plds[8][16][40];     // 10KB  P bounce (per-wave)

    const int tid = threadIdx.x;
    const int w   = tid >> 6;
    const int l   = tid & 63;
    const int li  = l & 15;
    const int lg  = l >> 4;

    // XCD-chunked bijective swizzle: each XCD gets 2 whole batches -> K/V L2-resident
    const int bid  = (int)blockIdx.x;
    const int bid2 = (bid & 7) * 32 + (bid >> 3);
    const int b    = bid2 >> 4;
    const int qt   = bid2 & 15;
    const int qbase = qt * QTB;

    const size_t bq   = (size_t)b * L_;
    const int    qrow = qbase + w * 16 + li;          // this lane's q row

    const float*  qp   = q  + (bq + qbase) * (size_t)D_;
    const bf16_t* kbp  = kb + bq * (size_t)D_;
    const float*  kp   = k  + bq * (size_t)D_;
    const bf16_t* vtp  = vt + (size_t)b * D_ * (size_t)L_;
    const float*  vp   = v  + bq * (size_t)D_;
    float* attnrow = attn + (bq + qrow) * (size_t)L_;
    float* outp    = out  + (bq + qbase) * (size_t)D_;

    // ---------------- Q B-fragments (pre-scaled by 1/temper)
    bf16x8 aq[4];
    #pragma unroll
    for (int ds = 0; ds < 4; ++ds) {
        const float* p = qp + (size_t)(w * 16 + li) * D_ + ds * 32 + lg * 8;
        f32x4 x0 = *(const f32x4*)p;
        f32x4 x1 = *(const f32x4*)(p + 4);
        bf16x8 a;
        #pragma unroll
        for (int u = 0; u < 4; ++u) {
            a[u]     = (bf16_t)(x0[u] * SCALE);
            a[4 + u] = (bf16_t)(x1[u] * SCALE);
        }
        aq[ds] = a;
    }

    // ---------------- cooperative staging geometry (per thread)
    const int krow = tid >> 4, kslot = tid & 15;      // K: [32][256B], 16B slots
    const int kdst = krow * 256 + ((kslot * 16) ^ ((krow & 7) << 4));
    const int mrow = tid >> 3, mslot = tid & 7;       // M: [128][128B], rows mrow, mrow+64
    const int mdst0 = mrow * 128 + ((mslot * 16) ^ ((mrow & 7) << 4));
    const int mdst1 = (mrow + 64) * 128 + ((mslot * 16) ^ ((mrow & 7) << 4));
    const int vrow = tid >> 2, vslot = tid & 3;       // V: [128][64B], no swz needed
    const int vdst = vrow * 64 + vslot * 16;

    const bf16_t* ksrcb = kbp + (size_t)krow * D_ + kslot * 8;
    const float*  ksrcf = kp  + (size_t)krow * D_ + kslot * 8;
    const int*    msrc0 = mask + (size_t)(bq + qbase + mrow) * L_ + mslot * 4;
    const int*    msrc1 = mask + (size_t)(bq + qbase + mrow + 64) * L_ + mslot * 4;
    const bf16_t* vsrcb = vtp + (size_t)vrow * L_ + vslot * 8;

    // issue (global->regs) / write (regs->LDS) helpers; slots static via A/B vars
    auto issueK = [&](int c, i32x4& ri, f32x4& rf0, f32x4& rf1) {
        if constexpr (WS) {
            ri = *(const i32x4*)(ksrcb + (size_t)c * 32 * D_);
        } else {
            rf0 = *(const f32x4*)(ksrcf + (size_t)c * 32 * D_);
            rf1 = *(const f32x4*)(ksrcf + (size_t)c * 32 * D_ + 4);
        }
    };
    auto writeK = [&](int sl, const i32x4& ri, const f32x4& rf0, const f32x4& rf1) {
        char* d = KstRaw + sl * 8192 + kdst;
        if constexpr (WS) {
            *(i32x4*)d = ri;
        } else {
            bf16x8 o;
            #pragma unroll
            for (int u = 0; u < 4; ++u) { o[u] = (bf16_t)rf0[u]; o[4+u] = (bf16_t)rf1[u]; }
            *(bf16x8*)d = o;
        }
    };
    auto issueM = [&](int c, i32x4& m0, i32x4& m1) {
        m0 = __builtin_nontemporal_load((const i32x4*)(msrc0 + c * 32));
        m1 = __builtin_nontemporal_load((const i32x4*)(msrc1 + c * 32));
    };
    auto writeM = [&](int sl, const i32x4& m0, const i32x4& m1) {
        *(i32x4*)(MVRaw + sl * 16384 + mdst0) = m0;
        *(i32x4*)(MVRaw + sl * 16384 + mdst1) = m1;
    };
    auto issueV = [&](int c, i32x4& ri, float (&vf)[8]) {
        if constexpr (WS) {
            ri = *(const i32x4*)(vsrcb + c * 32);
        } else {
            #pragma unroll
            for (int u = 0; u < 8; ++u)
                vf[u] = vp[(size_t)(c * 32 + vslot * 8 + u) * D_ + vrow];
        }
    };
    auto writeV = [&](int sl, const i32x4& ri, const float (&vf)[8]) {
        char* d = MVRaw + sl * 16384 + vdst;
        if constexpr (WS) {
            *(i32x4*)d = ri;
        } else {
            bf16x8 o;
            #pragma unroll
            for (int u = 0; u < 8; ++u) o[u] = (bf16_t)vf[u];
            *(bf16x8*)d = o;
        }
    };

    const int xr = (li & 7) << 4;   // read-side XOR (row&7 == li&7 for all our rows)

    // QK^T for chunk c from LDS slot -> a0 (k rows +0..15), a1 (+16..31)
    auto qkt = [&](int sl, f32x4& a0, f32x4& a1) {
        const char* Ks = KstRaw + sl * 8192;
        f32x4 r0 = {0.f,0.f,0.f,0.f}, r1 = {0.f,0.f,0.f,0.f};
        #pragma unroll
        for (int ds = 0; ds < 4; ++ds) {
            bf16x8 k0 = *(const bf16x8*)(Ks + li * 256 + ((ds * 64 + lg * 16) ^ xr));
            r0 = MFMA_BF16(k0, aq[ds], r0, 0, 0, 0);
        }
        #pragma unroll
        for (int ds = 0; ds < 4; ++ds) {
            bf16x8 k1 = *(const bf16x8*)(Ks + (16 + li) * 256 + ((ds * 64 + lg * 16) ^ xr));
            r1 = MFMA_BF16(k1, aq[ds], r1, 0, 0, 0);
        }
        a0 = r0; a1 = r1;
    };

    // ================= PASS 1: online masked max/sum ========================
    float m_run = -3.4e38f, l_run = 0.f;
    {
        unsigned mword = 0;
        auto p1c = [&](int c, int sl) {
            f32x4 a0, a1;
            qkt(sl, a0, a1);
            const char* Ms = MVRaw + sl * 16384 + (w * 16 + li) * 128;
            i32x4 va  = *(const i32x4*)(Ms + ((lg * 16) ^ xr));
            i32x4 vb_ = *(const i32x4*)(Ms + ((64 + lg * 16) ^ xr));
            unsigned byte =
                (va[0]  != 0 ?   1u : 0u) | (va[1]  != 0 ?   2u : 0u) |
                (va[2]  != 0 ?   4u : 0u) | (va[3]  != 0 ?   8u : 0u) |
                (vb_[0] != 0 ?  16u : 0u) | (vb_[1] != 0 ?  32u : 0u) |
                (vb_[2] != 0 ?  64u : 0u) | (vb_[3] != 0 ? 128u : 0u);
            float s0[4], s1[4];
            #pragma unroll
            for (int r = 0; r < 4; ++r) {
                s0[r] = a0[r] + (((byte >> r)       & 1u) ? 0.f : NEGINF);
                s1[r] = a1[r] + (((byte >> (4 + r)) & 1u) ? 0.f : NEGINF);
            }
            float mx = fmaxf(fmaxf(fmaxf(s0[0], s0[1]), fmaxf(s0[2], s0[3])),
                             fmaxf(fmaxf(s1[0], s1[1]), fmaxf(s1[2], s1[3])));
            mx = fmaxf(mx, m_run);
            float acc = 0.f;
            #pragma unroll
            for (int r = 0; r < 4; ++r)
                acc += __expf(s0[r] - mx) + __expf(s1[r] - mx);
            l_run = l_run * __expf(m_run - mx) + acc;
            m_run = mx;
            mword |= byte << ((c & 3) * 8);
            if ((c & 3) == 3) { mlds[w * 1024 + (c >> 2) * 64 + l] = mword; mword = 0; }
        };

        i32x4 kA{}, kB{}, mA0{}, mA1{}, mB0{}, mB1{};
        f32x4 kfA0{}, kfA1{}, kfB0{}, kfB1{};
        issueK(0, kA, kfA0, kfA1); issueM(0, mA0, mA1);
        issueK(1, kB, kfB0, kfB1); issueM(1, mB0, mB1);
        writeK(0, kA, kfA0, kfA1); writeM(0, mA0, mA1);
        BARRIER();
        int s0i = 0, s1i = 1, s2i = 2;
        #pragma unroll 1
        for (int c = 0; c < 64; c += 2) {
            if (c + 2 < 64) { issueK(c + 2, kA, kfA0, kfA1); issueM(c + 2, mA0, mA1); }
            writeK(s1i, kB, kfB0, kfB1); writeM(s1i, mB0, mB1);      // chunk c+1
            BARRIER();
            p1c(c, s0i);
            { int t = s0i; s0i = s1i; s1i = s2i; s2i = t; }
            if (c + 3 < 64) { issueK(c + 3, kB, kfB0, kfB1); issueM(c + 3, mB0, mB1); }
            if (c + 2 < 64) { writeK(s1i, kA, kfA0, kfA1); writeM(s1i, mA0, mA1); }
            BARRIER();
            p1c(c + 1, s0i);
            { int t = s0i; s0i = s1i; s1i = s2i; s2i = t; }
        }
    }

    // merge m/sum across the 4 lane-groups (lanes li, li+16, li+32, li+48)
    #pragma unroll
    for (int off = 16; off < 64; off <<= 1) {
        float mo = __shfl_xor(m_run, off);
        float lo = __shfl_xor(l_run, off);
        float mn = fmaxf(m_run, mo);
        l_run = l_run * __expf(m_run - mn) + lo * __expf(mo - mn);
        m_run = mn;
    }
    const float inv_l = 1.f / l_run;

    // ================= PASS 2: recompute + attn write + PV ==================
    f32x4 pv[8];
    #pragma unroll
    for (int dt = 0; dt < 8; ++dt) pv[dt] = {0.f, 0.f, 0.f, 0.f};

    {
        auto p2c = [&](int c, int sl) {
            f32x4 a0, a1;
            qkt(sl, a0, a1);
            const unsigned mw = mlds[w * 1024 + (c >> 2) * 64 + l];
            const unsigned byte = (mw >> ((c & 3) * 8)) & 0xffu;
            f32x4 o0, o1; bf16x4 pb0, pb1;
            #pragma unroll
            for (int r = 0; r < 4; ++r) {
                float sa = a0[r] + (((byte >> r)       & 1u) ? 0.f : NEGINF);
                float sb = a1[r] + (((byte >> (4 + r)) & 1u) ? 0.f : NEGINF);
                float p0 = __expf(sa - m_run);
                float p1 = __expf(sb - m_run);
                o0[r] = p0 * inv_l;  o1[r] = p1 * inv_l;
                pb0[r] = (bf16_t)p0; pb1[r] = (bf16_t)p1;
            }
            // attn: each 4-lane lg group covers one full 64B line per row
            __builtin_nontemporal_store(o0, (f32x4*)(attnrow + c * 32 + lg * 4));
            __builtin_nontemporal_store(o1, (f32x4*)(attnrow + c * 32 + 16 + lg * 4));
            // C-layout -> A-frag via per-wave LDS bounce
            *(bf16x4*)&plds[w][li][lg * 4]      = pb0;
            *(bf16x4*)&plds[w][li][16 + lg * 4] = pb1;
            bf16x8 pa = *(const bf16x8*)&plds[w][li][lg * 8];
            const char* Vs = MVRaw + sl * 16384;
            #pragma unroll
            for (int dt = 0; dt < 8; ++dt) {
                bf16x8 vbf = *(const bf16x8*)(Vs + (dt * 16 + li) * 64 + lg * 16);
                pv[dt] = MFMA_BF16(pa, vbf, pv[dt], 0, 0, 0);
            }
        };

        BARRIER();   // all pass-1 slab reads complete before restaging
        i32x4 kA{}, kB{}, vA{}, vB{};
        f32x4 kfA0{}, kfA1{}, kfB0{}, kfB1{};
        float vfA[8], vfB[8];
        issueK(0, kA, kfA0, kfA1); issueV(0, vA, vfA);
        issueK(1, kB, kfB0, kfB1); issueV(1, vB, vfB);
        writeK(0, kA, kfA0, kfA1); writeV(0, vA, vfA);
        BARRIER();
        int s0i = 0, s1i = 1, s2i = 2;
        #pragma unroll 1
        for (int c = 0; c < 64; c += 2) {
            if (c + 2 < 64) { issueK(c + 2, kA, kfA0, kfA1); issueV(c + 2, vA, vfA); }
            writeK(s1i, kB, kfB0, kfB1); writeV(s1i, vB, vfB);       // chunk c+1
            BARRIER();
            p2c(c, s0i);
            { int t = s0i; s0i = s1i; s1i = s2i; s2i = t; }
            if (c + 3 < 64) { issueK(c + 3, kB, kfB0, kfB1); issueV(c + 3, vB, vfB); }
            if (c + 2 < 64) { writeK(s1i, kA, kfA0, kfA1); writeV(s1i, vA, vfA); }
            BARRIER();
            p2c(c + 1, s0i);
            { int t = s0i; s0i = s1i; s1i = s2i; s2i = t; }
        }
    }

    // ---------------- Epilogue: out[q][d] = pv * inv_l[q]
    #pragma unroll
    for (int r = 0; r < 4; ++r) {
        const float il = __shfl(inv_l, lg * 4 + r);
        float* orow = outp + (size_t)(w * 16 + lg * 4 + r) * D_ + li;
        #pragma unroll
        for (int dt = 0; dt < 8; ++dt)
            __builtin_nontemporal_store(pv[dt][r] * il, orow + dt * 16);
    }
}

extern "C" void kernel_launch(void* const* d_in, const int* in_sizes, int n_in,
                              void* d_out, int out_size, void* d_ws, size_t ws_size,
                              hipStream_t stream) {
    const float* q    = (const float*)d_in[0];
    const float* k    = (const float*)d_in[1];
    const float* v    = (const float*)d_in[2];
    const int*   mask = (const int*)d_in[3];

    float* out  = (float*)d_out;
    float* attn = out + (size_t)B_ * L_ * D_;

    const size_t VT_BYTES = (size_t)B_ * D_ * L_ * 2;   // 8 MB
    const size_t KB_BYTES = (size_t)B_ * L_ * D_ * 2;   // 8 MB
    const bool ws_ok = ws_size >= VT_BYTES + KB_BYTES;
    bf16_t* vt = (bf16_t*)d_ws;
    bf16_t* kb = (bf16_t*)((char*)d_ws + VT_BYTES);

    if (ws_ok) {
        hipLaunchKernelGGL(prep_kernel, dim3(512), dim3(256), 0, stream, k, v, kb, vt);
        hipLaunchKernelGGL(sdpa_kernel<true>, dim3(256), dim3(512), 0, stream,
                           q, k, v, mask, kb, vt, out, attn);
    } else {
        hipLaunchKernelGGL(sdpa_kernel<false>, dim3(256), dim3(512), 0, stream,
                           q, k, v, mask, kb, vt, out, attn);
    }
}